// Round 15
// baseline (27.121 us; speedup 1.0000x reference)
//
#include <hip/hip_runtime.h>
#include <math.h>

// Problem constants (reference shapes are fixed)
#define S_LEN 2048
#define NH 4
#define BHN 16                      // NB*NH
#define E_DIM 12
#define NKB 16                      // key-split factor (128-key slices)
#define KEYS_PER_KB (S_LEN / NKB)   // 128
#define NQT 4                       // query tiles per (b,h)
#define QT_SIZE (S_LEN / NQT)       // 512 queries per block (8 per lane)
// Q pre-scale: log2(e)/sqrt(3) (softmax scale + exp->exp2) * 2^23 (Schraudolph)
#define QSCALE_EXP (0.8329931278350429f * 8388608.0f)
// Schraudolph bias: 127*2^23 + 383700 (centers multiplicative error to +-3.1%)
#define SCHRAUD_B 1065736916.0f

typedef float f32x2 __attribute__((ext_vector_type(2)));

// ---- packed f32 (VOP3P) helpers with op_sel broadcasts (VGPR operands) ----
// d = a * bcast(b.lo) + c
static __device__ __forceinline__ f32x2 pk_fma_blo(f32x2 a, f32x2 b, f32x2 c) {
    f32x2 d; asm("v_pk_fma_f32 %0, %1, %2, %3 op_sel_hi:[1,0,1]"
                 : "=v"(d) : "v"(a), "v"(b), "v"(c)); return d;
}
// d = a * bcast(b.hi) + c
static __device__ __forceinline__ f32x2 pk_fma_bhi(f32x2 a, f32x2 b, f32x2 c) {
    f32x2 d; asm("v_pk_fma_f32 %0, %1, %2, %3 op_sel:[0,1,0] op_sel_hi:[1,1,1]"
                 : "=v"(d) : "v"(a), "v"(b), "v"(c)); return d;
}
static __device__ __forceinline__ f32x2 pk_add2(f32x2 a, f32x2 b) {
    f32x2 d; asm("v_pk_add_f32 %0, %1, %2"
                 : "=v"(d) : "v"(a), "v"(b)); return d;
}

// per-(query-pair) step: score FMA chain seeded with Schraudolph bias ->
// full-rate cvt+bitcast exp -> PV (+denominator). K/V via LDS broadcast.
#define PAIR_STEP(QX,QY,QZ,AX,AY,AZ,AD) do {                       \
    f32x2 s_ = pk_fma_blo(QZ, kzw, Bv);                            \
    s_ = pk_fma_bhi(QY, kxy, s_);                                  \
    s_ = pk_fma_blo(QX, kxy, s_);                                  \
    f32x2 p_;                                                      \
    p_.x = __int_as_float((int)s_.x);                              \
    p_.y = __int_as_float((int)s_.y);                              \
    AX = pk_fma_blo(p_, vxy, AX);                                  \
    AY = pk_fma_bhi(p_, vxy, AY);                                  \
    AZ = pk_fma_blo(p_, vzw, AZ);                                  \
    AD = pk_add2(p_, AD);                                          \
} while (0)

// ---------------- Kernel 1: fused QKV-projection + attention partials ----------------
// grid = 16 bh x 4 qt x 16 kb = 1024 blocks of 256 threads, 4 blocks/CU
// (32KB LDS each). 8 queries/lane at FULL 16-wave/CU occupancy: halves the
// per-CU ds_read traffic vs R14 (the binding pipe) while keeping 4 waves/SIMD
// for latency hiding (R10's 8q/lane failed at 2 waves/SIMD).
__global__ __launch_bounds__(256, 4) void attn_kernel(
    const float* __restrict__ x,
    const float* __restrict__ wq, const float* __restrict__ wk,
    const float* __restrict__ wv, float4* __restrict__ part)
{
    __shared__ __align__(16) char smem[32768];
    float4* sK = (float4*)smem;              // [0, 2KB)    128 keys
    float4* sV = sK + KEYS_PER_KB;           // [2KB, 4KB)
    float4* sQ = sV + KEYS_PER_KB;           // [4KB, 12KB) 512 queries
    float*  sw = (float*)(smem + 12288);     // [12KB, +432B)
    float4* sAcc = (float4*)smem;            // overlay: 4 waves x 512 q = 32KB

    int tid = threadIdx.x;
    int kb = blockIdx.x & (NKB - 1);
    int qt = (blockIdx.x / NKB) & (NQT - 1);
    int bh = blockIdx.x / (NKB * NQT);
    int b  = bh >> 2;
    int h  = bh & 3;

    if (tid < 108) {
        int m = tid / 36;                    // 0=q, 1=k, 2=v
        int i = tid - m * 36;                // e*3 + d
        int e = i / 3, d = i - e * 3;
        const float* w = (m == 0) ? wq : (m == 1) ? wk : wv;
        sw[tid] = w[e * 12 + h * 3 + d];
    }
    __syncthreads();

    // ---- project K/V slice (128 keys, threads 0..127) ----
    if (tid < KEYS_PER_KB) {
        size_t kt = (size_t)b * S_LEN + kb * KEYS_PER_KB + tid;
        const float4* xp = (const float4*)(x + kt * E_DIM);
        float4 xa = xp[0], xb = xp[1], xc = xp[2];
        float xr[12] = {xa.x, xa.y, xa.z, xa.w, xb.x, xb.y, xb.z, xb.w, xc.x, xc.y, xc.z, xc.w};
        float k0 = 0, k1 = 0, k2 = 0, v0 = 0, v1 = 0, v2 = 0;
#pragma unroll
        for (int e = 0; e < 12; ++e) {
            float xe = xr[e];
            k0 = fmaf(xe, sw[36 + e * 3 + 0], k0);
            k1 = fmaf(xe, sw[36 + e * 3 + 1], k1);
            k2 = fmaf(xe, sw[36 + e * 3 + 2], k2);
            v0 = fmaf(xe, sw[72 + e * 3 + 0], v0);
            v1 = fmaf(xe, sw[72 + e * 3 + 1], v1);
            v2 = fmaf(xe, sw[72 + e * 3 + 2], v2);
        }
        sK[tid] = make_float4(k0, k1, k2, 0.0f);
        sV[tid] = make_float4(v0, v1, v2, 0.0f);
    }

    // ---- project Q tile (512 queries, 2 per thread) ----
#pragma unroll
    for (int rr = 0; rr < 2; ++rr) {
        int qi = rr * 256 + tid;
        size_t qtk = (size_t)b * S_LEN + qt * QT_SIZE + qi;
        const float4* xq = (const float4*)(x + qtk * E_DIM);
        float4 qa = xq[0], qb = xq[1], qc = xq[2];
        float qr[12] = {qa.x, qa.y, qa.z, qa.w, qb.x, qb.y, qb.z, qb.w, qc.x, qc.y, qc.z, qc.w};
        float q0 = 0, q1 = 0, q2 = 0;
#pragma unroll
        for (int e = 0; e < 12; ++e) {
            float xe = qr[e];
            q0 = fmaf(xe, sw[e * 3 + 0], q0);
            q1 = fmaf(xe, sw[e * 3 + 1], q1);
            q2 = fmaf(xe, sw[e * 3 + 2], q2);
        }
        sQ[qi] = make_float4(q0 * QSCALE_EXP, q1 * QSCALE_EXP, q2 * QSCALE_EXP, 0.0f);
    }
    __syncthreads();

    int w = tid >> 6;
    int lane = tid & 63;

    // 8 queries per lane -> 4 packed pairs
    float4 q0 = sQ[0 * 64 + lane], q1 = sQ[1 * 64 + lane];
    float4 q2 = sQ[2 * 64 + lane], q3 = sQ[3 * 64 + lane];
    float4 q4 = sQ[4 * 64 + lane], q5 = sQ[5 * 64 + lane];
    float4 q6 = sQ[6 * 64 + lane], q7 = sQ[7 * 64 + lane];
    f32x2 qx01 = {q0.x, q1.x}, qy01 = {q0.y, q1.y}, qz01 = {q0.z, q1.z};
    f32x2 qx23 = {q2.x, q3.x}, qy23 = {q2.y, q3.y}, qz23 = {q2.z, q3.z};
    f32x2 qx45 = {q4.x, q5.x}, qy45 = {q4.y, q5.y}, qz45 = {q4.z, q5.z};
    f32x2 qx67 = {q6.x, q7.x}, qy67 = {q6.y, q7.y}, qz67 = {q6.z, q7.z};

    const f32x2 Bv = {SCHRAUD_B, SCHRAUD_B};

    f32x2 ax01 = {0,0}, ay01 = {0,0}, az01 = {0,0}, ad01 = {0,0};
    f32x2 ax23 = {0,0}, ay23 = {0,0}, az23 = {0,0}, ad23 = {0,0};
    f32x2 ax45 = {0,0}, ay45 = {0,0}, az45 = {0,0}, ad45 = {0,0};
    f32x2 ax67 = {0,0}, ay67 = {0,0}, az67 = {0,0}, ad67 = {0,0};

    int kbeg = w * 32;                       // 32-key subrange per wave
#pragma unroll 4
    for (int j = 0; j < 32; ++j) {
        float4 kk = sK[kbeg + j];   // broadcast read (conflict-free)
        float4 vv = sV[kbeg + j];
        f32x2 kxy = {kk.x, kk.y}, kzw = {kk.z, kk.w};
        f32x2 vxy = {vv.x, vv.y}, vzw = {vv.z, vv.w};
        PAIR_STEP(qx01, qy01, qz01, ax01, ay01, az01, ad01);
        PAIR_STEP(qx23, qy23, qz23, ax23, ay23, az23, ad23);
        PAIR_STEP(qx45, qy45, qz45, ax45, ay45, az45, ad45);
        PAIR_STEP(qx67, qy67, qz67, ax67, ay67, az67, ad67);
    }

    __syncthreads();   // all waves done with sK/sV/sQ -> safe to overlay sAcc
    {
        float4* a = sAcc + w * QT_SIZE + lane;
        a[0 * 64] = make_float4(ax01.x, ay01.x, az01.x, ad01.x);
        a[1 * 64] = make_float4(ax01.y, ay01.y, az01.y, ad01.y);
        a[2 * 64] = make_float4(ax23.x, ay23.x, az23.x, ad23.x);
        a[3 * 64] = make_float4(ax23.y, ay23.y, az23.y, ad23.y);
        a[4 * 64] = make_float4(ax45.x, ay45.x, az45.x, ad45.x);
        a[5 * 64] = make_float4(ax45.y, ay45.y, az45.y, ad45.y);
        a[6 * 64] = make_float4(ax67.x, ay67.x, az67.x, ad67.x);
        a[7 * 64] = make_float4(ax67.y, ay67.y, az67.y, ad67.y);
    }
    __syncthreads();

    // cross-wave reduce (fixed order w0+w1+w2+w3), coalesced stores
#pragma unroll
    for (int rr = 0; rr < 2; ++rr) {
        int qq = rr * 256 + tid;
        float4 sum = sAcc[qq];
        float4 p1 = sAcc[QT_SIZE + qq];
        float4 p2 = sAcc[2 * QT_SIZE + qq];
        float4 p3 = sAcc[3 * QT_SIZE + qq];
        sum.x += p1.x + p2.x + p3.x;
        sum.y += p1.y + p2.y + p3.y;
        sum.z += p1.z + p2.z + p3.z;
        sum.w += p1.w + p2.w + p3.w;
        part[((size_t)kb * BHN + bh) * S_LEN + qt * QT_SIZE + qq] = sum;
    }
}

// ---------------- Kernel 2: fused tail ----------------
// 128 blocks x 64 threads; thread = one token. Merge 16 kb-partials per head
// (register batch of 16 loads per head), then the per-token tail chain.
// ring_z closed form: CNOT ring is GF(2)-linear; <Z_0> = prod_{j=1..11} cos(th_j),
// <Z_k> = prod_{j=0..k} cos(th_j) for k>=1.
__global__ __launch_bounds__(64) void tail_kernel(
    const float4* __restrict__ part, const float* __restrict__ x,
    const float* __restrict__ wo, const float* __restrict__ w1, const float* __restrict__ b1,
    const float* __restrict__ w2, const float* __restrict__ b2,
    const float* __restrict__ g1, const float* __restrict__ be1,
    const float* __restrict__ g2, const float* __restrict__ be2,
    float* __restrict__ out)
{
    __shared__ float swo[144], sw1[144], sw2[144];
    __shared__ float sb1[12], sb2[12], sg1[12], sbe1[12], sg2[12], sbe2[12];
    int tid = threadIdx.x;
    for (int i = tid; i < 144; i += 64) { swo[i] = wo[i]; sw1[i] = w1[i]; sw2[i] = w2[i]; }
    if (tid < 12) {
        sb1[tid] = b1[tid]; sb2[tid] = b2[tid];
        sg1[tid] = g1[tid]; sbe1[tid] = be1[tid];
        sg2[tid] = g2[tid]; sbe2[tid] = be2[tid];
    }

    int t = blockIdx.x * 64 + tid;           // token
    int b = t >> 11;
    int s = t & (S_LEN - 1);

    // merge key-split partials per head (16 loads batched), softmax division
    float o[12];
#pragma unroll
    for (int h = 0; h < NH; ++h) {
        float4 L[NKB];
#pragma unroll
        for (int kb = 0; kb < NKB; ++kb)
            L[kb] = part[((size_t)kb * BHN + (b * NH + h)) * S_LEN + s];
        float ax = 0, ay = 0, az = 0, aw = 0;
#pragma unroll
        for (int kb = 0; kb < NKB; ++kb) {
            ax += L[kb].x; ay += L[kb].y; az += L[kb].z; aw += L[kb].w;
        }
        float inv = 1.0f / aw;
        o[h * 3 + 0] = ax * inv;
        o[h * 3 + 1] = ay * inv;
        o[h * 3 + 2] = az * inv;
    }
    __syncthreads();   // weights staged

    // theta_k = o_k + o_{k%3}; c_k = cos(theta_k)
    float c[12];
#pragma unroll
    for (int k = 0; k < 12; ++k) c[k] = __cosf(o[k] + o[k % 3]);

    // ring_z closed form
    float z[12];
    {
        float p = c[0];
#pragma unroll
        for (int k = 1; k < 12; ++k) { p *= c[k]; z[k] = p; }
        p = c[1];
#pragma unroll
        for (int k = 2; k < 12; ++k) p *= c[k];
        z[0] = p;
    }

    // attn_out = z @ wo ; residual with x
    const float4* xp = (const float4*)(x + (size_t)t * E_DIM);
    float4 xa = xp[0], xb = xp[1], xc = xp[2];
    float xr[12] = {xa.x, xa.y, xa.z, xa.w, xb.x, xb.y, xb.z, xb.w, xc.x, xc.y, xc.z, xc.w};

    float y[12];
#pragma unroll
    for (int e = 0; e < 12; ++e) {
        float ao = 0;
#pragma unroll
        for (int k = 0; k < 12; ++k) ao = fmaf(z[k], swo[k * 12 + e], ao);
        y[e] = xr[e] + ao;
    }

    // LN1
    float mu = 0;
#pragma unroll
    for (int e = 0; e < 12; ++e) mu += y[e];
    mu *= (1.0f / 12.0f);
    float var = 0;
#pragma unroll
    for (int e = 0; e < 12; ++e) { float d = y[e] - mu; var = fmaf(d, d, var); }
    var *= (1.0f / 12.0f);
    float rs = rsqrtf(var + 1e-5f);
    float x1v[12];
#pragma unroll
    for (int e = 0; e < 12; ++e) x1v[e] = (y[e] - mu) * rs * sg1[e] + sbe1[e];

    // FFN: relu -> cos^2 -> w2
    float zq[12];
#pragma unroll
    for (int f = 0; f < 12; ++f) {
        float hd = sb1[f];
#pragma unroll
        for (int e = 0; e < 12; ++e) hd = fmaf(x1v[e], sw1[e * 12 + f], hd);
        hd = fmaxf(hd, 0.0f);
        float cc = __cosf(hd);
        zq[f] = cc * cc;
    }
    float y2[12];
#pragma unroll
    for (int e = 0; e < 12; ++e) {
        float fo = sb2[e];
#pragma unroll
        for (int f = 0; f < 12; ++f) fo = fmaf(zq[f], sw2[f * 12 + e], fo);
        y2[e] = x1v[e] + fo;
    }

    // LN2 -> out
    float mu2 = 0;
#pragma unroll
    for (int e = 0; e < 12; ++e) mu2 += y2[e];
    mu2 *= (1.0f / 12.0f);
    float var2 = 0;
#pragma unroll
    for (int e = 0; e < 12; ++e) { float d = y2[e] - mu2; var2 = fmaf(d, d, var2); }
    var2 *= (1.0f / 12.0f);
    float rs2 = rsqrtf(var2 + 1e-5f);

    float res[12];
#pragma unroll
    for (int e = 0; e < 12; ++e) res[e] = (y2[e] - mu2) * rs2 * sg2[e] + sbe2[e];

    float4* op = (float4*)(out + (size_t)t * E_DIM);
    op[0] = make_float4(res[0], res[1], res[2], res[3]);
    op[1] = make_float4(res[4], res[5], res[6], res[7]);
    op[2] = make_float4(res[8], res[9], res[10], res[11]);
}

extern "C" void kernel_launch(void* const* d_in, const int* in_sizes, int n_in,
                              void* d_out, int out_size, void* d_ws, size_t ws_size,
                              hipStream_t stream)
{
    const float* x   = (const float*)d_in[0];
    const float* wq  = (const float*)d_in[1];
    const float* wk  = (const float*)d_in[2];
    const float* wv  = (const float*)d_in[3];
    const float* wo  = (const float*)d_in[4];
    const float* w1  = (const float*)d_in[5];
    const float* b1  = (const float*)d_in[6];
    const float* w2  = (const float*)d_in[7];
    const float* b2  = (const float*)d_in[8];
    const float* g1  = (const float*)d_in[9];
    const float* be1 = (const float*)d_in[10];
    const float* g2  = (const float*)d_in[11];
    const float* be2 = (const float*)d_in[12];

    float4* part = (float4*)d_ws;   // NKB*BHN*S_LEN float4 = 8MB

    attn_kernel<<<BHN * NQT * NKB, 256, 0, stream>>>(x, wq, wk, wv, part);
    tail_kernel<<<128, 64, 0, stream>>>(part, x, wo, w1, b1, w2, b2,
                                        g1, be1, g2, be2, (float*)d_out);
}

// Round 16
// 26.981 us; speedup vs baseline: 1.0052x; 1.0052x over previous
//
#include <hip/hip_runtime.h>
#include <math.h>

// Problem constants (reference shapes are fixed)
#define S_LEN 2048
#define NH 4
#define BHN 16                      // NB*NH
#define E_DIM 12
#define NKB 16                      // key-split factor (128-key slices)
#define KEYS_PER_KB (S_LEN / NKB)   // 128
#define NQT 8                       // query tiles per (b,h)
#define QT_SIZE (S_LEN / NQT)       // 256 queries per block (4 per lane)
// Q pre-scale: log2(e)/sqrt(3) (softmax scale + exp->exp2) * 2^23 (Schraudolph)
#define QSCALE_EXP (0.8329931278350429f * 8388608.0f)
// Schraudolph bias: 127*2^23 + 383700 (centers multiplicative error to +-3.1%)
#define SCHRAUD_B 1065736916.0f

typedef float f32x2 __attribute__((ext_vector_type(2)));

// ---- packed f32 (VOP3P) helpers with op_sel broadcasts (VGPR operands) ----
// d = a * bcast(b.lo) + c
static __device__ __forceinline__ f32x2 pk_fma_blo(f32x2 a, f32x2 b, f32x2 c) {
    f32x2 d; asm("v_pk_fma_f32 %0, %1, %2, %3 op_sel_hi:[1,0,1]"
                 : "=v"(d) : "v"(a), "v"(b), "v"(c)); return d;
}
// d = a * bcast(b.hi) + c
static __device__ __forceinline__ f32x2 pk_fma_bhi(f32x2 a, f32x2 b, f32x2 c) {
    f32x2 d; asm("v_pk_fma_f32 %0, %1, %2, %3 op_sel:[0,1,0] op_sel_hi:[1,1,1]"
                 : "=v"(d) : "v"(a), "v"(b), "v"(c)); return d;
}
static __device__ __forceinline__ f32x2 pk_add2(f32x2 a, f32x2 b) {
    f32x2 d; asm("v_pk_add_f32 %0, %1, %2"
                 : "=v"(d) : "v"(a), "v"(b)); return d;
}

// per-(query-pair) step: score FMA chain seeded with Schraudolph bias ->
// full-rate cvt+bitcast exp -> PV (+denominator). K/V via LDS broadcast.
#define PAIR_STEP(QX,QY,QZ,AX,AY,AZ,AD) do {                       \
    f32x2 s_ = pk_fma_blo(QZ, kzw, Bv);                            \
    s_ = pk_fma_bhi(QY, kxy, s_);                                  \
    s_ = pk_fma_blo(QX, kxy, s_);                                  \
    f32x2 p_;                                                      \
    p_.x = __int_as_float((int)s_.x);                              \
    p_.y = __int_as_float((int)s_.y);                              \
    AX = pk_fma_blo(p_, vxy, AX);                                  \
    AY = pk_fma_bhi(p_, vxy, AY);                                  \
    AZ = pk_fma_blo(p_, vzw, AZ);                                  \
    AD = pk_add2(p_, AD);                                          \
} while (0)

// ---------------- Kernel 1: fused QKV-projection + attention partials ----------------
// grid = 16 bh x 8 qt x 16 kb = 2048 blocks of 256 threads -> 8 blocks/CU =
// 8 waves/SIMD (2x R14's occupancy). Inner math byte-identical to R14; the
// dep chain (3 FMA -> cvt -> 4 FMA) is latency-exposed at 4 waves/SIMD, and
// doubling resident waves is the one lever not yet tried.
__global__ __launch_bounds__(256, 8) void attn_kernel(
    const float* __restrict__ x,
    const float* __restrict__ wq, const float* __restrict__ wk,
    const float* __restrict__ wv, float4* __restrict__ part)
{
    __shared__ __align__(16) char smem[16384];
    float4* sK = (float4*)smem;              // [0, 2KB)    128 keys
    float4* sV = sK + KEYS_PER_KB;           // [2KB, 4KB)
    float4* sQ = sV + KEYS_PER_KB;           // [4KB, 8KB)  256 queries
    float*  sw = (float*)(smem + 8192);      // [8KB, +432B)
    float4* sAcc = (float4*)smem;            // overlay: 4 waves x 256 q = 16KB

    int tid = threadIdx.x;
    int kb = blockIdx.x & (NKB - 1);
    int qt = (blockIdx.x / NKB) & (NQT - 1);
    int bh = blockIdx.x / (NKB * NQT);
    int b  = bh >> 2;
    int h  = bh & 3;

    if (tid < 108) {
        int m = tid / 36;                    // 0=q, 1=k, 2=v
        int i = tid - m * 36;                // e*3 + d
        int e = i / 3, d = i - e * 3;
        const float* w = (m == 0) ? wq : (m == 1) ? wk : wv;
        sw[tid] = w[e * 12 + h * 3 + d];
    }
    __syncthreads();

    // ---- project K/V slice (128 keys, threads 0..127) and Q tile (256 q) ----
    if (tid < KEYS_PER_KB) {
        size_t kt = (size_t)b * S_LEN + kb * KEYS_PER_KB + tid;
        const float4* xp = (const float4*)(x + kt * E_DIM);
        float4 xa = xp[0], xb = xp[1], xc = xp[2];
        float xr[12] = {xa.x, xa.y, xa.z, xa.w, xb.x, xb.y, xb.z, xb.w, xc.x, xc.y, xc.z, xc.w};
        float k0 = 0, k1 = 0, k2 = 0, v0 = 0, v1 = 0, v2 = 0;
#pragma unroll
        for (int e = 0; e < 12; ++e) {
            float xe = xr[e];
            k0 = fmaf(xe, sw[36 + e * 3 + 0], k0);
            k1 = fmaf(xe, sw[36 + e * 3 + 1], k1);
            k2 = fmaf(xe, sw[36 + e * 3 + 2], k2);
            v0 = fmaf(xe, sw[72 + e * 3 + 0], v0);
            v1 = fmaf(xe, sw[72 + e * 3 + 1], v1);
            v2 = fmaf(xe, sw[72 + e * 3 + 2], v2);
        }
        sK[tid] = make_float4(k0, k1, k2, 0.0f);
        sV[tid] = make_float4(v0, v1, v2, 0.0f);
    }
    {
        size_t qtk = (size_t)b * S_LEN + qt * QT_SIZE + tid;
        const float4* xq = (const float4*)(x + qtk * E_DIM);
        float4 qa = xq[0], qb = xq[1], qc = xq[2];
        float qr[12] = {qa.x, qa.y, qa.z, qa.w, qb.x, qb.y, qb.z, qb.w, qc.x, qc.y, qc.z, qc.w};
        float q0 = 0, q1 = 0, q2 = 0;
#pragma unroll
        for (int e = 0; e < 12; ++e) {
            float xe = qr[e];
            q0 = fmaf(xe, sw[e * 3 + 0], q0);
            q1 = fmaf(xe, sw[e * 3 + 1], q1);
            q2 = fmaf(xe, sw[e * 3 + 2], q2);
        }
        sQ[tid] = make_float4(q0 * QSCALE_EXP, q1 * QSCALE_EXP, q2 * QSCALE_EXP, 0.0f);
    }
    __syncthreads();

    int w = tid >> 6;
    int lane = tid & 63;

    // pack query pairs: lanes' queries r=0..3 -> pairs (0,1) and (2,3)
    float4 q0 = sQ[0 * 64 + lane];
    float4 q1 = sQ[1 * 64 + lane];
    float4 q2 = sQ[2 * 64 + lane];
    float4 q3 = sQ[3 * 64 + lane];
    f32x2 qx01 = {q0.x, q1.x}, qy01 = {q0.y, q1.y}, qz01 = {q0.z, q1.z};
    f32x2 qx23 = {q2.x, q3.x}, qy23 = {q2.y, q3.y}, qz23 = {q2.z, q3.z};

    const f32x2 Bv = {SCHRAUD_B, SCHRAUD_B};

    f32x2 ax01 = {0,0}, ay01 = {0,0}, az01 = {0,0}, ad01 = {0,0};
    f32x2 ax23 = {0,0}, ay23 = {0,0}, az23 = {0,0}, ad23 = {0,0};

    int kbeg = w * 32;                       // 32-key subrange per wave
#pragma unroll 4
    for (int j = 0; j < 32; ++j) {
        float4 kk = sK[kbeg + j];   // broadcast read (conflict-free)
        float4 vv = sV[kbeg + j];
        f32x2 kxy = {kk.x, kk.y}, kzw = {kk.z, kk.w};
        f32x2 vxy = {vv.x, vv.y}, vzw = {vv.z, vv.w};
        PAIR_STEP(qx01, qy01, qz01, ax01, ay01, az01, ad01);
        PAIR_STEP(qx23, qy23, qz23, ax23, ay23, az23, ad23);
    }

    // all waves done reading sK/sV/sQ -> safe to overlay sAcc
    __syncthreads();
    sAcc[w * QT_SIZE + 0 * 64 + lane] = make_float4(ax01.x, ay01.x, az01.x, ad01.x);
    sAcc[w * QT_SIZE + 1 * 64 + lane] = make_float4(ax01.y, ay01.y, az01.y, ad01.y);
    sAcc[w * QT_SIZE + 2 * 64 + lane] = make_float4(ax23.x, ay23.x, az23.x, ad23.x);
    sAcc[w * QT_SIZE + 3 * 64 + lane] = make_float4(ax23.y, ay23.y, az23.y, ad23.y);
    __syncthreads();

    float4 sum = sAcc[tid];
    float4 p1 = sAcc[QT_SIZE + tid];
    float4 p2 = sAcc[2 * QT_SIZE + tid];
    float4 p3 = sAcc[3 * QT_SIZE + tid];
    sum.x += p1.x + p2.x + p3.x;
    sum.y += p1.y + p2.y + p3.y;
    sum.z += p1.z + p2.z + p3.z;
    sum.w += p1.w + p2.w + p3.w;

    part[((size_t)kb * BHN + bh) * S_LEN + qt * QT_SIZE + tid] = sum;
}

// ---------------- Kernel 2: fused tail ----------------
// 128 blocks x 64 threads; thread = one token. Merge 16 kb-partials per head
// (register batch of 16 loads), then the per-token tail chain.
// ring_z closed form: CNOT ring is GF(2)-linear; <Z_0> = prod_{j=1..11} cos(th_j),
// <Z_k> = prod_{j=0..k} cos(th_j) for k>=1.
__global__ __launch_bounds__(64) void tail_kernel(
    const float4* __restrict__ part, const float* __restrict__ x,
    const float* __restrict__ wo, const float* __restrict__ w1, const float* __restrict__ b1,
    const float* __restrict__ w2, const float* __restrict__ b2,
    const float* __restrict__ g1, const float* __restrict__ be1,
    const float* __restrict__ g2, const float* __restrict__ be2,
    float* __restrict__ out)
{
    __shared__ float swo[144], sw1[144], sw2[144];
    __shared__ float sb1[12], sb2[12], sg1[12], sbe1[12], sg2[12], sbe2[12];
    int tid = threadIdx.x;
    for (int i = tid; i < 144; i += 64) { swo[i] = wo[i]; sw1[i] = w1[i]; sw2[i] = w2[i]; }
    if (tid < 12) {
        sb1[tid] = b1[tid]; sb2[tid] = b2[tid];
        sg1[tid] = g1[tid]; sbe1[tid] = be1[tid];
        sg2[tid] = g2[tid]; sbe2[tid] = be2[tid];
    }

    int t = blockIdx.x * 64 + tid;           // token
    int b = t >> 11;
    int s = t & (S_LEN - 1);

    // merge key-split partials per head (16 loads batched), softmax division
    float o[12];
#pragma unroll
    for (int h = 0; h < NH; ++h) {
        float4 L[NKB];
#pragma unroll
        for (int kb = 0; kb < NKB; ++kb)
            L[kb] = part[((size_t)kb * BHN + (b * NH + h)) * S_LEN + s];
        float ax = 0, ay = 0, az = 0, aw = 0;
#pragma unroll
        for (int kb = 0; kb < NKB; ++kb) {
            ax += L[kb].x; ay += L[kb].y; az += L[kb].z; aw += L[kb].w;
        }
        float inv = 1.0f / aw;
        o[h * 3 + 0] = ax * inv;
        o[h * 3 + 1] = ay * inv;
        o[h * 3 + 2] = az * inv;
    }
    __syncthreads();   // weights staged

    // theta_k = o_k + o_{k%3}; c_k = cos(theta_k)
    float c[12];
#pragma unroll
    for (int k = 0; k < 12; ++k) c[k] = __cosf(o[k] + o[k % 3]);

    // ring_z closed form
    float z[12];
    {
        float p = c[0];
#pragma unroll
        for (int k = 1; k < 12; ++k) { p *= c[k]; z[k] = p; }
        p = c[1];
#pragma unroll
        for (int k = 2; k < 12; ++k) p *= c[k];
        z[0] = p;
    }

    // attn_out = z @ wo ; residual with x
    const float4* xp = (const float4*)(x + (size_t)t * E_DIM);
    float4 xa = xp[0], xb = xp[1], xc = xp[2];
    float xr[12] = {xa.x, xa.y, xa.z, xa.w, xb.x, xb.y, xb.z, xb.w, xc.x, xc.y, xc.z, xc.w};

    float y[12];
#pragma unroll
    for (int e = 0; e < 12; ++e) {
        float ao = 0;
#pragma unroll
        for (int k = 0; k < 12; ++k) ao = fmaf(z[k], swo[k * 12 + e], ao);
        y[e] = xr[e] + ao;
    }

    // LN1
    float mu = 0;
#pragma unroll
    for (int e = 0; e < 12; ++e) mu += y[e];
    mu *= (1.0f / 12.0f);
    float var = 0;
#pragma unroll
    for (int e = 0; e < 12; ++e) { float d = y[e] - mu; var = fmaf(d, d, var); }
    var *= (1.0f / 12.0f);
    float rs = rsqrtf(var + 1e-5f);
    float x1v[12];
#pragma unroll
    for (int e = 0; e < 12; ++e) x1v[e] = (y[e] - mu) * rs * sg1[e] + sbe1[e];

    // FFN: relu -> cos^2 -> w2
    float zq[12];
#pragma unroll
    for (int f = 0; f < 12; ++f) {
        float hd = sb1[f];
#pragma unroll
        for (int e = 0; e < 12; ++e) hd = fmaf(x1v[e], sw1[e * 12 + f], hd);
        hd = fmaxf(hd, 0.0f);
        float cc = __cosf(hd);
        zq[f] = cc * cc;
    }
    float y2[12];
#pragma unroll
    for (int e = 0; e < 12; ++e) {
        float fo = sb2[e];
#pragma unroll
        for (int f = 0; f < 12; ++f) fo = fmaf(zq[f], sw2[f * 12 + e], fo);
        y2[e] = x1v[e] + fo;
    }

    // LN2 -> out
    float mu2 = 0;
#pragma unroll
    for (int e = 0; e < 12; ++e) mu2 += y2[e];
    mu2 *= (1.0f / 12.0f);
    float var2 = 0;
#pragma unroll
    for (int e = 0; e < 12; ++e) { float d = y2[e] - mu2; var2 = fmaf(d, d, var2); }
    var2 *= (1.0f / 12.0f);
    float rs2 = rsqrtf(var2 + 1e-5f);

    float res[12];
#pragma unroll
    for (int e = 0; e < 12; ++e) res[e] = (y2[e] - mu2) * rs2 * sg2[e] + sbe2[e];

    float4* op = (float4*)(out + (size_t)t * E_DIM);
    op[0] = make_float4(res[0], res[1], res[2], res[3]);
    op[1] = make_float4(res[4], res[5], res[6], res[7]);
    op[2] = make_float4(res[8], res[9], res[10], res[11]);
}

extern "C" void kernel_launch(void* const* d_in, const int* in_sizes, int n_in,
                              void* d_out, int out_size, void* d_ws, size_t ws_size,
                              hipStream_t stream)
{
    const float* x   = (const float*)d_in[0];
    const float* wq  = (const float*)d_in[1];
    const float* wk  = (const float*)d_in[2];
    const float* wv  = (const float*)d_in[3];
    const float* wo  = (const float*)d_in[4];
    const float* w1  = (const float*)d_in[5];
    const float* b1  = (const float*)d_in[6];
    const float* w2  = (const float*)d_in[7];
    const float* b2  = (const float*)d_in[8];
    const float* g1  = (const float*)d_in[9];
    const float* be1 = (const float*)d_in[10];
    const float* g2  = (const float*)d_in[11];
    const float* be2 = (const float*)d_in[12];

    float4* part = (float4*)d_ws;   // NKB*BHN*S_LEN float4 = 8MB

    attn_kernel<<<BHN * NQT * NKB, 256, 0, stream>>>(x, wq, wk, wv, part);
    tail_kernel<<<128, 64, 0, stream>>>(part, x, wo, w1, b1, w2, b2,
                                        g1, be1, g2, be2, (float*)d_out);
}

// Round 17
// 24.660 us; speedup vs baseline: 1.0998x; 1.0941x over previous
//
#include <hip/hip_runtime.h>
#include <math.h>

// Problem constants (reference shapes are fixed)
#define S_LEN 2048
#define NH 4
#define BHN 16                      // NB*NH
#define E_DIM 12
#define NKB 8                       // key-split factor
#define KEYS_PER_KB (S_LEN / NKB)   // 256
#define NQT 8                       // query tiles per (b,h)
#define QT_SIZE (S_LEN / NQT)       // 256 queries per block (4 per lane)
// Q pre-scale: log2(e)/sqrt(3) (softmax scale + exp->exp2) * 2^23 (Schraudolph)
#define QSCALE_EXP (0.8329931278350429f * 8388608.0f)
// Schraudolph bias: 127*2^23 + 383700 (centers multiplicative error to +-3.1%)
#define SCHRAUD_B 1065736916.0f

typedef float f32x2 __attribute__((ext_vector_type(2)));

// ---- packed f32 (VOP3P) helpers with op_sel broadcasts (VGPR operands) ----
// d = a * bcast(b.lo) + c
static __device__ __forceinline__ f32x2 pk_fma_blo(f32x2 a, f32x2 b, f32x2 c) {
    f32x2 d; asm("v_pk_fma_f32 %0, %1, %2, %3 op_sel_hi:[1,0,1]"
                 : "=v"(d) : "v"(a), "v"(b), "v"(c)); return d;
}
// d = a * bcast(b.hi) + c
static __device__ __forceinline__ f32x2 pk_fma_bhi(f32x2 a, f32x2 b, f32x2 c) {
    f32x2 d; asm("v_pk_fma_f32 %0, %1, %2, %3 op_sel:[0,1,0] op_sel_hi:[1,1,1]"
                 : "=v"(d) : "v"(a), "v"(b), "v"(c)); return d;
}
static __device__ __forceinline__ f32x2 pk_add2(f32x2 a, f32x2 b) {
    f32x2 d; asm("v_pk_add_f32 %0, %1, %2"
                 : "=v"(d) : "v"(a), "v"(b)); return d;
}

// per-(query-pair) step: score FMA chain seeded with Schraudolph bias ->
// full-rate cvt+bitcast exp -> PV (+denominator). K/V via LDS broadcast
// (R13 proved VALU broadcasts regress; LDS pipe overlaps with VALU).
#define PAIR_STEP(QX,QY,QZ,AX,AY,AZ,AD) do {                       \
    f32x2 s_ = pk_fma_blo(QZ, kzw, Bv);                            \
    s_ = pk_fma_bhi(QY, kxy, s_);                                  \
    s_ = pk_fma_blo(QX, kxy, s_);                                  \
    f32x2 p_;                                                      \
    p_.x = __int_as_float((int)s_.x);                              \
    p_.y = __int_as_float((int)s_.y);                              \
    AX = pk_fma_blo(p_, vxy, AX);                                  \
    AY = pk_fma_bhi(p_, vxy, AY);                                  \
    AZ = pk_fma_blo(p_, vzw, AZ);                                  \
    AD = pk_add2(p_, AD);                                          \
} while (0)

// ---------------- Kernel 1: fused QKV-projection + attention partials ----------------
// R14 configuration (best measured: 24.2 us): grid = 16 bh x 8 qt x 8 kb =
// 1024 blocks of 256 threads, 4 queries/lane, 16KB LDS overlay, lb(256,6).
// Single change vs R14: inner unroll 4 -> 8 (more independent score-chains
// in flight against ds_read/VALU latency).
__global__ __launch_bounds__(256, 6) void attn_kernel(
    const float* __restrict__ x,
    const float* __restrict__ wq, const float* __restrict__ wk,
    const float* __restrict__ wv, float4* __restrict__ part)
{
    __shared__ __align__(16) char smem[16384];
    float4* sK  = (float4*)smem;            // [0,   4KB)
    float4* sV  = sK + KEYS_PER_KB;         // [4KB, 8KB)
    float4* sQ  = sV + KEYS_PER_KB;         // [8KB,12KB)
    float*  sw  = (float*)(smem + 12288);   // [12KB, +432B)
    float4* sAcc = (float4*)smem;           // overlay, 16KB (after barrier)

    int tid = threadIdx.x;
    int kb = blockIdx.x & (NKB - 1);
    int qt = (blockIdx.x / NKB) & (NQT - 1);
    int bh = blockIdx.x / (NKB * NQT);
    int b  = bh >> 2;
    int h  = bh & 3;

    if (tid < 108) {
        int m = tid / 36;                    // 0=q, 1=k, 2=v
        int i = tid - m * 36;                // e*3 + d
        int e = i / 3, d = i - e * 3;
        const float* w = (m == 0) ? wq : (m == 1) ? wk : wv;
        sw[tid] = w[e * 12 + h * 3 + d];
    }
    __syncthreads();

    // ---- project this block's K/V slice and Q tile ----
    {
        size_t kt = (size_t)b * S_LEN + kb * KEYS_PER_KB + tid;
        const float4* xp = (const float4*)(x + kt * E_DIM);
        float4 xa = xp[0], xb = xp[1], xc = xp[2];
        float xr[12] = {xa.x, xa.y, xa.z, xa.w, xb.x, xb.y, xb.z, xb.w, xc.x, xc.y, xc.z, xc.w};
        float k0 = 0, k1 = 0, k2 = 0, v0 = 0, v1 = 0, v2 = 0;
#pragma unroll
        for (int e = 0; e < 12; ++e) {
            float xe = xr[e];
            k0 = fmaf(xe, sw[36 + e * 3 + 0], k0);
            k1 = fmaf(xe, sw[36 + e * 3 + 1], k1);
            k2 = fmaf(xe, sw[36 + e * 3 + 2], k2);
            v0 = fmaf(xe, sw[72 + e * 3 + 0], v0);
            v1 = fmaf(xe, sw[72 + e * 3 + 1], v1);
            v2 = fmaf(xe, sw[72 + e * 3 + 2], v2);
        }
        sK[tid] = make_float4(k0, k1, k2, 0.0f);
        sV[tid] = make_float4(v0, v1, v2, 0.0f);

        size_t qtk = (size_t)b * S_LEN + qt * QT_SIZE + tid;
        const float4* xq = (const float4*)(x + qtk * E_DIM);
        float4 qa = xq[0], qb = xq[1], qc = xq[2];
        float qr[12] = {qa.x, qa.y, qa.z, qa.w, qb.x, qb.y, qb.z, qb.w, qc.x, qc.y, qc.z, qc.w};
        float q0 = 0, q1 = 0, q2 = 0;
#pragma unroll
        for (int e = 0; e < 12; ++e) {
            float xe = qr[e];
            q0 = fmaf(xe, sw[e * 3 + 0], q0);
            q1 = fmaf(xe, sw[e * 3 + 1], q1);
            q2 = fmaf(xe, sw[e * 3 + 2], q2);
        }
        sQ[tid] = make_float4(q0 * QSCALE_EXP, q1 * QSCALE_EXP, q2 * QSCALE_EXP, 0.0f);
    }
    __syncthreads();

    int w = tid >> 6;
    int lane = tid & 63;

    // pack query pairs: lanes' queries r=0..3 -> pairs (0,1) and (2,3)
    float4 q0 = sQ[0 * 64 + lane];
    float4 q1 = sQ[1 * 64 + lane];
    float4 q2 = sQ[2 * 64 + lane];
    float4 q3 = sQ[3 * 64 + lane];
    f32x2 qx01 = {q0.x, q1.x}, qy01 = {q0.y, q1.y}, qz01 = {q0.z, q1.z};
    f32x2 qx23 = {q2.x, q3.x}, qy23 = {q2.y, q3.y}, qz23 = {q2.z, q3.z};

    const f32x2 Bv = {SCHRAUD_B, SCHRAUD_B};

    f32x2 ax01 = {0,0}, ay01 = {0,0}, az01 = {0,0}, ad01 = {0,0};
    f32x2 ax23 = {0,0}, ay23 = {0,0}, az23 = {0,0}, ad23 = {0,0};

    int kbeg = w * 64;
#pragma unroll 8
    for (int j = 0; j < 64; ++j) {
        float4 kk = sK[kbeg + j];   // broadcast read (conflict-free)
        float4 vv = sV[kbeg + j];
        f32x2 kxy = {kk.x, kk.y}, kzw = {kk.z, kk.w};
        f32x2 vxy = {vv.x, vv.y}, vzw = {vv.z, vv.w};
        PAIR_STEP(qx01, qy01, qz01, ax01, ay01, az01, ad01);
        PAIR_STEP(qx23, qy23, qz23, ax23, ay23, az23, ad23);
    }

    // all waves done reading sK/sV -> safe to overlay sAcc
    __syncthreads();
    sAcc[w * QT_SIZE + 0 * 64 + lane] = make_float4(ax01.x, ay01.x, az01.x, ad01.x);
    sAcc[w * QT_SIZE + 1 * 64 + lane] = make_float4(ax01.y, ay01.y, az01.y, ad01.y);
    sAcc[w * QT_SIZE + 2 * 64 + lane] = make_float4(ax23.x, ay23.x, az23.x, ad23.x);
    sAcc[w * QT_SIZE + 3 * 64 + lane] = make_float4(ax23.y, ay23.y, az23.y, ad23.y);
    __syncthreads();

    float4 sum = sAcc[tid];
    float4 p1 = sAcc[QT_SIZE + tid];
    float4 p2 = sAcc[2 * QT_SIZE + tid];
    float4 p3 = sAcc[3 * QT_SIZE + tid];
    sum.x += p1.x + p2.x + p3.x;
    sum.y += p1.y + p2.y + p3.y;
    sum.z += p1.z + p2.z + p3.z;
    sum.w += p1.w + p2.w + p3.w;

    part[((size_t)kb * BHN + bh) * S_LEN + qt * QT_SIZE + tid] = sum;
}

// ---------------- Kernel 2: fused tail (batched partial loads) ----------------
// 128 blocks x 64 threads; thread = one token.
// ring_z closed form: CNOT ring is GF(2)-linear; <Z_0> = prod_{j=1..11} cos(th_j),
// <Z_k> = prod_{j=0..k} cos(th_j) for k>=1.
__global__ __launch_bounds__(64) void tail_kernel(
    const float4* __restrict__ part, const float* __restrict__ x,
    const float* __restrict__ wo, const float* __restrict__ w1, const float* __restrict__ b1,
    const float* __restrict__ w2, const float* __restrict__ b2,
    const float* __restrict__ g1, const float* __restrict__ be1,
    const float* __restrict__ g2, const float* __restrict__ be2,
    float* __restrict__ out)
{
    __shared__ float swo[144], sw1[144], sw2[144];
    __shared__ float sb1[12], sb2[12], sg1[12], sbe1[12], sg2[12], sbe2[12];
    int tid = threadIdx.x;
    for (int i = tid; i < 144; i += 64) { swo[i] = wo[i]; sw1[i] = w1[i]; sw2[i] = w2[i]; }
    if (tid < 12) {
        sb1[tid] = b1[tid]; sb2[tid] = b2[tid];
        sg1[tid] = g1[tid]; sbe1[tid] = be1[tid];
        sg2[tid] = g2[tid]; sbe2[tid] = be2[tid];
    }

    int t = blockIdx.x * 64 + tid;           // token
    int b = t >> 11;
    int s = t & (S_LEN - 1);

    // batched load of all 32 partials (issue all, then use)
    float4 L[32];
#pragma unroll
    for (int h = 0; h < NH; ++h)
#pragma unroll
        for (int kb = 0; kb < NKB; ++kb)
            L[h * NKB + kb] = part[((size_t)kb * BHN + (b * NH + h)) * S_LEN + s];

    __syncthreads();   // weights staged (overlapped with load latency)

    // merge key-split partials, finish softmax division
    float o[12];
#pragma unroll
    for (int h = 0; h < NH; ++h) {
        float ax = 0, ay = 0, az = 0, aw = 0;
#pragma unroll
        for (int kb = 0; kb < NKB; ++kb) {
            float4 p = L[h * NKB + kb];
            ax += p.x; ay += p.y; az += p.z; aw += p.w;
        }
        float inv = 1.0f / aw;
        o[h * 3 + 0] = ax * inv;
        o[h * 3 + 1] = ay * inv;
        o[h * 3 + 2] = az * inv;
    }

    // theta_k = o_k + o_{k%3}; c_k = cos(theta_k)
    float c[12];
#pragma unroll
    for (int k = 0; k < 12; ++k) c[k] = __cosf(o[k] + o[k % 3]);

    // ring_z closed form (CNOT ring is GF(2)-linear)
    float z[12];
    {
        float p = c[0];
#pragma unroll
        for (int k = 1; k < 12; ++k) { p *= c[k]; z[k] = p; }
        p = c[1];
#pragma unroll
        for (int k = 2; k < 12; ++k) p *= c[k];
        z[0] = p;
    }

    // attn_out = z @ wo ; residual with x
    const float4* xp = (const float4*)(x + (size_t)t * E_DIM);
    float4 xa = xp[0], xb = xp[1], xc = xp[2];
    float xr[12] = {xa.x, xa.y, xa.z, xa.w, xb.x, xb.y, xb.z, xb.w, xc.x, xc.y, xc.z, xc.w};

    float y[12];
#pragma unroll
    for (int e = 0; e < 12; ++e) {
        float ao = 0;
#pragma unroll
        for (int k = 0; k < 12; ++k) ao = fmaf(z[k], swo[k * 12 + e], ao);
        y[e] = xr[e] + ao;
    }

    // LN1
    float mu = 0;
#pragma unroll
    for (int e = 0; e < 12; ++e) mu += y[e];
    mu *= (1.0f / 12.0f);
    float var = 0;
#pragma unroll
    for (int e = 0; e < 12; ++e) { float d = y[e] - mu; var = fmaf(d, d, var); }
    var *= (1.0f / 12.0f);
    float rs = rsqrtf(var + 1e-5f);
    float x1v[12];
#pragma unroll
    for (int e = 0; e < 12; ++e) x1v[e] = (y[e] - mu) * rs * sg1[e] + sbe1[e];

    // FFN: relu -> cos^2 -> w2
    float zq[12];
#pragma unroll
    for (int f = 0; f < 12; ++f) {
        float hd = sb1[f];
#pragma unroll
        for (int e = 0; e < 12; ++e) hd = fmaf(x1v[e], sw1[e * 12 + f], hd);
        hd = fmaxf(hd, 0.0f);
        float cc = __cosf(hd);
        zq[f] = cc * cc;
    }
    float y2[12];
#pragma unroll
    for (int e = 0; e < 12; ++e) {
        float fo = sb2[e];
#pragma unroll
        for (int f = 0; f < 12; ++f) fo = fmaf(zq[f], sw2[f * 12 + e], fo);
        y2[e] = x1v[e] + fo;
    }

    // LN2 -> out
    float mu2 = 0;
#pragma unroll
    for (int e = 0; e < 12; ++e) mu2 += y2[e];
    mu2 *= (1.0f / 12.0f);
    float var2 = 0;
#pragma unroll
    for (int e = 0; e < 12; ++e) { float d = y2[e] - mu2; var2 = fmaf(d, d, var2); }
    var2 *= (1.0f / 12.0f);
    float rs2 = rsqrtf(var2 + 1e-5f);

    float res[12];
#pragma unroll
    for (int e = 0; e < 12; ++e) res[e] = (y2[e] - mu2) * rs2 * sg2[e] + sbe2[e];

    float4* op = (float4*)(out + (size_t)t * E_DIM);
    op[0] = make_float4(res[0], res[1], res[2], res[3]);
    op[1] = make_float4(res[4], res[5], res[6], res[7]);
    op[2] = make_float4(res[8], res[9], res[10], res[11]);
}

extern "C" void kernel_launch(void* const* d_in, const int* in_sizes, int n_in,
                              void* d_out, int out_size, void* d_ws, size_t ws_size,
                              hipStream_t stream)
{
    const float* x   = (const float*)d_in[0];
    const float* wq  = (const float*)d_in[1];
    const float* wk  = (const float*)d_in[2];
    const float* wv  = (const float*)d_in[3];
    const float* wo  = (const float*)d_in[4];
    const float* w1  = (const float*)d_in[5];
    const float* b1  = (const float*)d_in[6];
    const float* w2  = (const float*)d_in[7];
    const float* b2  = (const float*)d_in[8];
    const float* g1  = (const float*)d_in[9];
    const float* be1 = (const float*)d_in[10];
    const float* g2  = (const float*)d_in[11];
    const float* be2 = (const float*)d_in[12];

    float4* part = (float4*)d_ws;   // NKB*BHN*S_LEN float4 = 4MB

    attn_kernel<<<BHN * NQT * NKB, 256, 0, stream>>>(x, wq, wk, wv, part);
    tail_kernel<<<128, 64, 0, stream>>>(part, x, wo, w1, b1, w2, b2,
                                        g1, be1, g2, be2, (float*)d_out);
}

// Round 18
// 24.172 us; speedup vs baseline: 1.1220x; 1.0202x over previous
//
#include <hip/hip_runtime.h>
#include <math.h>

// Problem constants (reference shapes are fixed)
#define S_LEN 2048
#define NH 4
#define BHN 16                      // NB*NH
#define E_DIM 12
#define NKB 8                       // key-split factor
#define KEYS_PER_KB (S_LEN / NKB)   // 256
#define NQT 8                       // query tiles per (b,h)
#define QT_SIZE (S_LEN / NQT)       // 256 queries per block (4 per lane)
// Q pre-scale: log2(e)/sqrt(3) (softmax scale + exp->exp2) * 2^23 (Schraudolph)
#define QSCALE_EXP (0.8329931278350429f * 8388608.0f)
// Schraudolph bias: 127*2^23 + 383700 (centers multiplicative error to +-3.1%)
#define SCHRAUD_B 1065736916.0f

typedef float f32x2 __attribute__((ext_vector_type(2)));

// ---- packed f32 (VOP3P) helpers with op_sel broadcasts (VGPR operands) ----
// d = a * bcast(b.lo) + c
static __device__ __forceinline__ f32x2 pk_fma_blo(f32x2 a, f32x2 b, f32x2 c) {
    f32x2 d; asm("v_pk_fma_f32 %0, %1, %2, %3 op_sel_hi:[1,0,1]"
                 : "=v"(d) : "v"(a), "v"(b), "v"(c)); return d;
}
// d = a * bcast(b.hi) + c
static __device__ __forceinline__ f32x2 pk_fma_bhi(f32x2 a, f32x2 b, f32x2 c) {
    f32x2 d; asm("v_pk_fma_f32 %0, %1, %2, %3 op_sel:[0,1,0] op_sel_hi:[1,1,1]"
                 : "=v"(d) : "v"(a), "v"(b), "v"(c)); return d;
}
static __device__ __forceinline__ f32x2 pk_add2(f32x2 a, f32x2 b) {
    f32x2 d; asm("v_pk_add_f32 %0, %1, %2"
                 : "=v"(d) : "v"(a), "v"(b)); return d;
}

// per-(query-pair) step: score FMA chain seeded with Schraudolph bias ->
// full-rate cvt+bitcast exp -> PV (+denominator). K/V via LDS broadcast
// (R13 proved VALU broadcasts regress; LDS pipe overlaps with VALU).
#define PAIR_STEP(QX,QY,QZ,AX,AY,AZ,AD) do {                       \
    f32x2 s_ = pk_fma_blo(QZ, kzw, Bv);                            \
    s_ = pk_fma_bhi(QY, kxy, s_);                                  \
    s_ = pk_fma_blo(QX, kxy, s_);                                  \
    f32x2 p_;                                                      \
    p_.x = __int_as_float((int)s_.x);                              \
    p_.y = __int_as_float((int)s_.y);                              \
    AX = pk_fma_blo(p_, vxy, AX);                                  \
    AY = pk_fma_bhi(p_, vxy, AY);                                  \
    AZ = pk_fma_blo(p_, vzw, AZ);                                  \
    AD = pk_add2(p_, AD);                                          \
} while (0)

// ---------------- Kernel 1: fused QKV-projection + attention partials ----------------
// R14 configuration (best measured: 24.2 us): grid = 16 bh x 8 qt x 8 kb =
// 1024 blocks of 256 threads, 4 queries/lane, 16KB LDS overlay, lb(256,6),
// inner unroll 4. Verified local optimum: LDS-halving x2, VALU-broadcast,
// occupancy x2 and x0.5, unroll x2, and two fusion schemes all regressed.
__global__ __launch_bounds__(256, 6) void attn_kernel(
    const float* __restrict__ x,
    const float* __restrict__ wq, const float* __restrict__ wk,
    const float* __restrict__ wv, float4* __restrict__ part)
{
    __shared__ __align__(16) char smem[16384];
    float4* sK  = (float4*)smem;            // [0,   4KB)
    float4* sV  = sK + KEYS_PER_KB;         // [4KB, 8KB)
    float4* sQ  = sV + KEYS_PER_KB;         // [8KB,12KB)
    float*  sw  = (float*)(smem + 12288);   // [12KB, +432B)
    float4* sAcc = (float4*)smem;           // overlay, 16KB (after barrier)

    int tid = threadIdx.x;
    int kb = blockIdx.x & (NKB - 1);
    int qt = (blockIdx.x / NKB) & (NQT - 1);
    int bh = blockIdx.x / (NKB * NQT);
    int b  = bh >> 2;
    int h  = bh & 3;

    if (tid < 108) {
        int m = tid / 36;                    // 0=q, 1=k, 2=v
        int i = tid - m * 36;                // e*3 + d
        int e = i / 3, d = i - e * 3;
        const float* w = (m == 0) ? wq : (m == 1) ? wk : wv;
        sw[tid] = w[e * 12 + h * 3 + d];
    }
    __syncthreads();

    // ---- project this block's K/V slice and Q tile ----
    {
        size_t kt = (size_t)b * S_LEN + kb * KEYS_PER_KB + tid;
        const float4* xp = (const float4*)(x + kt * E_DIM);
        float4 xa = xp[0], xb = xp[1], xc = xp[2];
        float xr[12] = {xa.x, xa.y, xa.z, xa.w, xb.x, xb.y, xb.z, xb.w, xc.x, xc.y, xc.z, xc.w};
        float k0 = 0, k1 = 0, k2 = 0, v0 = 0, v1 = 0, v2 = 0;
#pragma unroll
        for (int e = 0; e < 12; ++e) {
            float xe = xr[e];
            k0 = fmaf(xe, sw[36 + e * 3 + 0], k0);
            k1 = fmaf(xe, sw[36 + e * 3 + 1], k1);
            k2 = fmaf(xe, sw[36 + e * 3 + 2], k2);
            v0 = fmaf(xe, sw[72 + e * 3 + 0], v0);
            v1 = fmaf(xe, sw[72 + e * 3 + 1], v1);
            v2 = fmaf(xe, sw[72 + e * 3 + 2], v2);
        }
        sK[tid] = make_float4(k0, k1, k2, 0.0f);
        sV[tid] = make_float4(v0, v1, v2, 0.0f);

        size_t qtk = (size_t)b * S_LEN + qt * QT_SIZE + tid;
        const float4* xq = (const float4*)(x + qtk * E_DIM);
        float4 qa = xq[0], qb = xq[1], qc = xq[2];
        float qr[12] = {qa.x, qa.y, qa.z, qa.w, qb.x, qb.y, qb.z, qb.w, qc.x, qc.y, qc.z, qc.w};
        float q0 = 0, q1 = 0, q2 = 0;
#pragma unroll
        for (int e = 0; e < 12; ++e) {
            float xe = qr[e];
            q0 = fmaf(xe, sw[e * 3 + 0], q0);
            q1 = fmaf(xe, sw[e * 3 + 1], q1);
            q2 = fmaf(xe, sw[e * 3 + 2], q2);
        }
        sQ[tid] = make_float4(q0 * QSCALE_EXP, q1 * QSCALE_EXP, q2 * QSCALE_EXP, 0.0f);
    }
    __syncthreads();

    int w = tid >> 6;
    int lane = tid & 63;

    // pack query pairs: lanes' queries r=0..3 -> pairs (0,1) and (2,3)
    float4 q0 = sQ[0 * 64 + lane];
    float4 q1 = sQ[1 * 64 + lane];
    float4 q2 = sQ[2 * 64 + lane];
    float4 q3 = sQ[3 * 64 + lane];
    f32x2 qx01 = {q0.x, q1.x}, qy01 = {q0.y, q1.y}, qz01 = {q0.z, q1.z};
    f32x2 qx23 = {q2.x, q3.x}, qy23 = {q2.y, q3.y}, qz23 = {q2.z, q3.z};

    const f32x2 Bv = {SCHRAUD_B, SCHRAUD_B};

    f32x2 ax01 = {0,0}, ay01 = {0,0}, az01 = {0,0}, ad01 = {0,0};
    f32x2 ax23 = {0,0}, ay23 = {0,0}, az23 = {0,0}, ad23 = {0,0};

    int kbeg = w * 64;
#pragma unroll 4
    for (int j = 0; j < 64; ++j) {
        float4 kk = sK[kbeg + j];   // broadcast read (conflict-free)
        float4 vv = sV[kbeg + j];
        f32x2 kxy = {kk.x, kk.y}, kzw = {kk.z, kk.w};
        f32x2 vxy = {vv.x, vv.y}, vzw = {vv.z, vv.w};
        PAIR_STEP(qx01, qy01, qz01, ax01, ay01, az01, ad01);
        PAIR_STEP(qx23, qy23, qz23, ax23, ay23, az23, ad23);
    }

    // all waves done reading sK/sV -> safe to overlay sAcc
    __syncthreads();
    sAcc[w * QT_SIZE + 0 * 64 + lane] = make_float4(ax01.x, ay01.x, az01.x, ad01.x);
    sAcc[w * QT_SIZE + 1 * 64 + lane] = make_float4(ax01.y, ay01.y, az01.y, ad01.y);
    sAcc[w * QT_SIZE + 2 * 64 + lane] = make_float4(ax23.x, ay23.x, az23.x, ad23.x);
    sAcc[w * QT_SIZE + 3 * 64 + lane] = make_float4(ax23.y, ay23.y, az23.y, ad23.y);
    __syncthreads();

    float4 sum = sAcc[tid];
    float4 p1 = sAcc[QT_SIZE + tid];
    float4 p2 = sAcc[2 * QT_SIZE + tid];
    float4 p3 = sAcc[3 * QT_SIZE + tid];
    sum.x += p1.x + p2.x + p3.x;
    sum.y += p1.y + p2.y + p3.y;
    sum.z += p1.z + p2.z + p3.z;
    sum.w += p1.w + p2.w + p3.w;

    part[((size_t)kb * BHN + bh) * S_LEN + qt * QT_SIZE + tid] = sum;
}

// ---------------- Kernel 2: fused tail (batched partial loads) ----------------
// 128 blocks x 64 threads; thread = one token.
// ring_z closed form: CNOT ring is GF(2)-linear; <Z_0> = prod_{j=1..11} cos(th_j),
// <Z_k> = prod_{j=0..k} cos(th_j) for k>=1.
__global__ __launch_bounds__(64) void tail_kernel(
    const float4* __restrict__ part, const float* __restrict__ x,
    const float* __restrict__ wo, const float* __restrict__ w1, const float* __restrict__ b1,
    const float* __restrict__ w2, const float* __restrict__ b2,
    const float* __restrict__ g1, const float* __restrict__ be1,
    const float* __restrict__ g2, const float* __restrict__ be2,
    float* __restrict__ out)
{
    __shared__ float swo[144], sw1[144], sw2[144];
    __shared__ float sb1[12], sb2[12], sg1[12], sbe1[12], sg2[12], sbe2[12];
    int tid = threadIdx.x;
    for (int i = tid; i < 144; i += 64) { swo[i] = wo[i]; sw1[i] = w1[i]; sw2[i] = w2[i]; }
    if (tid < 12) {
        sb1[tid] = b1[tid]; sb2[tid] = b2[tid];
        sg1[tid] = g1[tid]; sbe1[tid] = be1[tid];
        sg2[tid] = g2[tid]; sbe2[tid] = be2[tid];
    }

    int t = blockIdx.x * 64 + tid;           // token
    int b = t >> 11;
    int s = t & (S_LEN - 1);

    // batched load of all 32 partials (issue all, then use)
    float4 L[32];
#pragma unroll
    for (int h = 0; h < NH; ++h)
#pragma unroll
        for (int kb = 0; kb < NKB; ++kb)
            L[h * NKB + kb] = part[((size_t)kb * BHN + (b * NH + h)) * S_LEN + s];

    __syncthreads();   // weights staged (overlapped with load latency)

    // merge key-split partials, finish softmax division
    float o[12];
#pragma unroll
    for (int h = 0; h < NH; ++h) {
        float ax = 0, ay = 0, az = 0, aw = 0;
#pragma unroll
        for (int kb = 0; kb < NKB; ++kb) {
            float4 p = L[h * NKB + kb];
            ax += p.x; ay += p.y; az += p.z; aw += p.w;
        }
        float inv = 1.0f / aw;
        o[h * 3 + 0] = ax * inv;
        o[h * 3 + 1] = ay * inv;
        o[h * 3 + 2] = az * inv;
    }

    // theta_k = o_k + o_{k%3}; c_k = cos(theta_k)
    float c[12];
#pragma unroll
    for (int k = 0; k < 12; ++k) c[k] = __cosf(o[k] + o[k % 3]);

    // ring_z closed form (CNOT ring is GF(2)-linear)
    float z[12];
    {
        float p = c[0];
#pragma unroll
        for (int k = 1; k < 12; ++k) { p *= c[k]; z[k] = p; }
        p = c[1];
#pragma unroll
        for (int k = 2; k < 12; ++k) p *= c[k];
        z[0] = p;
    }

    // attn_out = z @ wo ; residual with x
    const float4* xp = (const float4*)(x + (size_t)t * E_DIM);
    float4 xa = xp[0], xb = xp[1], xc = xp[2];
    float xr[12] = {xa.x, xa.y, xa.z, xa.w, xb.x, xb.y, xb.z, xb.w, xc.x, xc.y, xc.z, xc.w};

    float y[12];
#pragma unroll
    for (int e = 0; e < 12; ++e) {
        float ao = 0;
#pragma unroll
        for (int k = 0; k < 12; ++k) ao = fmaf(z[k], swo[k * 12 + e], ao);
        y[e] = xr[e] + ao;
    }

    // LN1
    float mu = 0;
#pragma unroll
    for (int e = 0; e < 12; ++e) mu += y[e];
    mu *= (1.0f / 12.0f);
    float var = 0;
#pragma unroll
    for (int e = 0; e < 12; ++e) { float d = y[e] - mu; var = fmaf(d, d, var); }
    var *= (1.0f / 12.0f);
    float rs = rsqrtf(var + 1e-5f);
    float x1v[12];
#pragma unroll
    for (int e = 0; e < 12; ++e) x1v[e] = (y[e] - mu) * rs * sg1[e] + sbe1[e];

    // FFN: relu -> cos^2 -> w2
    float zq[12];
#pragma unroll
    for (int f = 0; f < 12; ++f) {
        float hd = sb1[f];
#pragma unroll
        for (int e = 0; e < 12; ++e) hd = fmaf(x1v[e], sw1[e * 12 + f], hd);
        hd = fmaxf(hd, 0.0f);
        float cc = __cosf(hd);
        zq[f] = cc * cc;
    }
    float y2[12];
#pragma unroll
    for (int e = 0; e < 12; ++e) {
        float fo = sb2[e];
#pragma unroll
        for (int f = 0; f < 12; ++f) fo = fmaf(zq[f], sw2[f * 12 + e], fo);
        y2[e] = x1v[e] + fo;
    }

    // LN2 -> out
    float mu2 = 0;
#pragma unroll
    for (int e = 0; e < 12; ++e) mu2 += y2[e];
    mu2 *= (1.0f / 12.0f);
    float var2 = 0;
#pragma unroll
    for (int e = 0; e < 12; ++e) { float d = y2[e] - mu2; var2 = fmaf(d, d, var2); }
    var2 *= (1.0f / 12.0f);
    float rs2 = rsqrtf(var2 + 1e-5f);

    float res[12];
#pragma unroll
    for (int e = 0; e < 12; ++e) res[e] = (y2[e] - mu2) * rs2 * sg2[e] + sbe2[e];

    float4* op = (float4*)(out + (size_t)t * E_DIM);
    op[0] = make_float4(res[0], res[1], res[2], res[3]);
    op[1] = make_float4(res[4], res[5], res[6], res[7]);
    op[2] = make_float4(res[8], res[9], res[10], res[11]);
}

extern "C" void kernel_launch(void* const* d_in, const int* in_sizes, int n_in,
                              void* d_out, int out_size, void* d_ws, size_t ws_size,
                              hipStream_t stream)
{
    const float* x   = (const float*)d_in[0];
    const float* wq  = (const float*)d_in[1];
    const float* wk  = (const float*)d_in[2];
    const float* wv  = (const float*)d_in[3];
    const float* wo  = (const float*)d_in[4];
    const float* w1  = (const float*)d_in[5];
    const float* b1  = (const float*)d_in[6];
    const float* w2  = (const float*)d_in[7];
    const float* b2  = (const float*)d_in[8];
    const float* g1  = (const float*)d_in[9];
    const float* be1 = (const float*)d_in[10];
    const float* g2  = (const float*)d_in[11];
    const float* be2 = (const float*)d_in[12];

    float4* part = (float4*)d_ws;   // NKB*BHN*S_LEN float4 = 4MB

    attn_kernel<<<BHN * NQT * NKB, 256, 0, stream>>>(x, wq, wk, wv, part);
    tail_kernel<<<128, 64, 0, stream>>>(part, x, wo, w1, b1, w2, b2,
                                        g1, be1, g2, be2, (float*)d_out);
}